// Round 2
// baseline (1332.079 us; speedup 1.0000x reference)
//
#include <hip/hip_runtime.h>

#define NN 100000
#define EE 3200000
#define FF 128

// ---------------------------------------------------------------- degrees
// exact mapping: thread t handles edges [4t, 4t+4) — 4 independent atomics
__global__ __launch_bounds__(256) void k_degrees(const int* __restrict__ ei,
                                                 int* __restrict__ deg_out,
                                                 int* __restrict__ deg_in) {
  int t = blockIdx.x * blockDim.x + threadIdx.x;
  int e = t * 4;
  if (e >= EE) return;
  int4 s = *(const int4*)(ei + e);
  int4 d = *(const int4*)(ei + EE + e);
  atomicAdd(&deg_out[s.x], 1);
  atomicAdd(&deg_out[s.y], 1);
  atomicAdd(&deg_out[s.z], 1);
  atomicAdd(&deg_out[s.w], 1);
  atomicAdd(&deg_in[d.x], 1);
  atomicAdd(&deg_in[d.y], 1);
  atomicAdd(&deg_in[d.z], 1);
  atomicAdd(&deg_in[d.w], 1);
}

// ---------------------------------------------------------------- norm scales
__global__ __launch_bounds__(256) void k_scales(const int* __restrict__ deg_out,
                                                const int* __restrict__ deg_in,
                                                float* __restrict__ dout_is,
                                                float* __restrict__ din_is) {
  int i = blockIdx.x * blockDim.x + threadIdx.x;
  if (i < NN) {
    int doo = deg_out[i]; if (doo < 1) doo = 1;
    int dii = deg_in[i];  if (dii < 1) dii = 1;
    dout_is[i] = rsqrtf((float)doo);
    din_is[i]  = rsqrtf((float)dii);
  }
}

// ---------------------------------------------------------------- exclusive scan (single block)
// writes offs[0..NN] and cursor[0..NN-1] (= offs) in one pass
__global__ __launch_bounds__(1024) void k_scan(const int* __restrict__ deg,
                                               int* __restrict__ offs,
                                               int* __restrict__ cursor) {
  __shared__ int sums[1024];
  const int T = 1024;
  const int per = (NN + T - 1) / T;   // 98
  int tid = threadIdx.x;
  int start = tid * per;
  int end = start + per; if (end > NN) end = NN;
  if (start > NN) start = NN;
  int s = 0;
  for (int i = start; i < end; ++i) s += deg[i];
  sums[tid] = s;
  __syncthreads();
  for (int off = 1; off < T; off <<= 1) {
    int v = (tid >= off) ? sums[tid - off] : 0;
    __syncthreads();
    sums[tid] += v;
    __syncthreads();
  }
  int run = (tid == 0) ? 0 : sums[tid - 1];
  for (int i = start; i < end; ++i) {
    offs[i] = run; cursor[i] = run; run += deg[i];
  }
  if (tid == T - 1) offs[NN] = run;
}

// ---------------------------------------------------------------- CSR scatter
// exact mapping, 4 edges/thread, 4 independent atomic chains
__global__ __launch_bounds__(256) void k_scatter(const int* __restrict__ ei,
                                                 int* __restrict__ cursor,
                                                 int* __restrict__ csr_src) {
  int t = blockIdx.x * blockDim.x + threadIdx.x;
  int e = t * 4;
  if (e >= EE) return;
  int4 s = *(const int4*)(ei + e);
  int4 d = *(const int4*)(ei + EE + e);
  int p0 = atomicAdd(&cursor[d.x], 1);
  int p1 = atomicAdd(&cursor[d.y], 1);
  int p2 = atomicAdd(&cursor[d.z], 1);
  int p3 = atomicAdd(&cursor[d.w], 1);
  csr_src[p0] = s.x;
  csr_src[p1] = s.y;
  csr_src[p2] = s.z;
  csr_src[p3] = s.w;
}

// ---------------------------------------------------------------- prescale
// out[i][:] = x[i][:] * dout_is[i]   (one float4 per thread)
__global__ __launch_bounds__(256) void k_prescale(const float* __restrict__ x,
                                                  const float* __restrict__ dout_is,
                                                  float* __restrict__ out) {
  int t = blockIdx.x * blockDim.x + threadIdx.x;
  if (t >= NN * (FF / 4)) return;
  int node = t >> 5;                 // FF/4 = 32 float4 per row
  float sc = dout_is[node];
  float4 v = ((const float4*)x)[t];
  v.x *= sc; v.y *= sc; v.z *= sc; v.w *= sc;
  ((float4*)out)[t] = v;
}

// ---------------------------------------------------------------- pull aggregation
// out[i] = din_is[i] * sum_{e in in(i)} xs[src(e)]     (xs pre-scaled by dout_is)
// one wave per node, float2 per lane; 8-deep gather unroll
__global__ __launch_bounds__(256) void k_agg(const float* __restrict__ xs,
                                             const float* __restrict__ din_is,
                                             const int* __restrict__ offs,
                                             const int* __restrict__ csr_src,
                                             float* __restrict__ out) {
  int gid = blockIdx.x * blockDim.x + threadIdx.x;
  int node = gid >> 6;
  int lane = threadIdx.x & 63;
  if (node >= NN) return;
  int beg = offs[node], end = offs[node + 1];
  float ax = 0.f, ay = 0.f, bx = 0.f, by = 0.f;
  int e = beg;
  // head-peel to 16B-align the csr_src int4 reads
  for (; e < end && (e & 3); ++e) {
    int s = csr_src[e];
    float2 v = *(const float2*)(xs + (size_t)s * FF + lane * 2);
    ax += v.x; ay += v.y;
  }
  for (; e + 8 <= end; e += 8) {
    int4 i0 = *(const int4*)(csr_src + e);
    int4 i1 = *(const int4*)(csr_src + e + 4);
    float2 v0 = *(const float2*)(xs + (size_t)i0.x * FF + lane * 2);
    float2 v1 = *(const float2*)(xs + (size_t)i0.y * FF + lane * 2);
    float2 v2 = *(const float2*)(xs + (size_t)i0.z * FF + lane * 2);
    float2 v3 = *(const float2*)(xs + (size_t)i0.w * FF + lane * 2);
    float2 v4 = *(const float2*)(xs + (size_t)i1.x * FF + lane * 2);
    float2 v5 = *(const float2*)(xs + (size_t)i1.y * FF + lane * 2);
    float2 v6 = *(const float2*)(xs + (size_t)i1.z * FF + lane * 2);
    float2 v7 = *(const float2*)(xs + (size_t)i1.w * FF + lane * 2);
    ax += v0.x; ay += v0.y; bx += v1.x; by += v1.y;
    ax += v2.x; ay += v2.y; bx += v3.x; by += v3.y;
    ax += v4.x; ay += v4.y; bx += v5.x; by += v5.y;
    ax += v6.x; ay += v6.y; bx += v7.x; by += v7.y;
  }
  for (; e < end; ++e) {
    int s = csr_src[e];
    float2 v = *(const float2*)(xs + (size_t)s * FF + lane * 2);
    ax += v.x; ay += v.y;
  }
  float di = din_is[node];
  float2 r; r.x = (ax + bx) * di; r.y = (ay + by) * di;
  *(float2*)(out + node * FF + lane * 2) = r;
}

// ---------------------------------------------------------------- GEMM + bias + PReLU (+ optional row postscale)
__global__ __launch_bounds__(256) void k_gemm(const float* __restrict__ X,
                                              const float* __restrict__ W,
                                              const float* __restrict__ bias,
                                              const float* __restrict__ pa,
                                              const float* __restrict__ postscale,
                                              int do_post,
                                              float* __restrict__ out) {
  __shared__ float Xs[64][FF + 1];
  __shared__ float Wt[32][FF];
  int tid = threadIdx.x;
  int row0 = blockIdx.x * 64;

  for (int t = tid; t < 64 * (FF / 4); t += 256) {
    int r = t >> 5;
    int c4 = (t & 31) * 4;
    int row = row0 + r;
    float4 v = make_float4(0.f, 0.f, 0.f, 0.f);
    if (row < NN) v = *(const float4*)(X + row * FF + c4);
    Xs[r][c4 + 0] = v.x; Xs[r][c4 + 1] = v.y; Xs[r][c4 + 2] = v.z; Xs[r][c4 + 3] = v.w;
  }

  int rp = tid >> 3;
  int ia = rp * 2, ib = ia + 1;
  int j0 = (tid & 7) * 4;

  float4 acc0q0 = make_float4(0,0,0,0), acc0q1 = acc0q0, acc0q2 = acc0q0, acc0q3 = acc0q0;
  float4 acc1q0 = acc0q0, acc1q1 = acc0q0, acc1q2 = acc0q0, acc1q3 = acc0q0;

  for (int kt = 0; kt < 4; ++kt) {
    __syncthreads();
    {
      const float4* W4 = (const float4*)(W + kt * 32 * FF);
      float4* Wt4 = (float4*)(&Wt[0][0]);
      for (int t = tid; t < 32 * FF / 4; t += 256) Wt4[t] = W4[t];
    }
    __syncthreads();
#pragma unroll
    for (int k = 0; k < 32; ++k) {
      float xa = Xs[ia][kt * 32 + k];
      float xb = Xs[ib][kt * 32 + k];
      float4 w0 = *(const float4*)(&Wt[k][j0 + 0]);
      float4 w1 = *(const float4*)(&Wt[k][j0 + 32]);
      float4 w2 = *(const float4*)(&Wt[k][j0 + 64]);
      float4 w3 = *(const float4*)(&Wt[k][j0 + 96]);
      acc0q0.x = fmaf(xa, w0.x, acc0q0.x); acc0q0.y = fmaf(xa, w0.y, acc0q0.y);
      acc0q0.z = fmaf(xa, w0.z, acc0q0.z); acc0q0.w = fmaf(xa, w0.w, acc0q0.w);
      acc0q1.x = fmaf(xa, w1.x, acc0q1.x); acc0q1.y = fmaf(xa, w1.y, acc0q1.y);
      acc0q1.z = fmaf(xa, w1.z, acc0q1.z); acc0q1.w = fmaf(xa, w1.w, acc0q1.w);
      acc0q2.x = fmaf(xa, w2.x, acc0q2.x); acc0q2.y = fmaf(xa, w2.y, acc0q2.y);
      acc0q2.z = fmaf(xa, w2.z, acc0q2.z); acc0q2.w = fmaf(xa, w2.w, acc0q2.w);
      acc0q3.x = fmaf(xa, w3.x, acc0q3.x); acc0q3.y = fmaf(xa, w3.y, acc0q3.y);
      acc0q3.z = fmaf(xa, w3.z, acc0q3.z); acc0q3.w = fmaf(xa, w3.w, acc0q3.w);
      acc1q0.x = fmaf(xb, w0.x, acc1q0.x); acc1q0.y = fmaf(xb, w0.y, acc1q0.y);
      acc1q0.z = fmaf(xb, w0.z, acc1q0.z); acc1q0.w = fmaf(xb, w0.w, acc1q0.w);
      acc1q1.x = fmaf(xb, w1.x, acc1q1.x); acc1q1.y = fmaf(xb, w1.y, acc1q1.y);
      acc1q1.z = fmaf(xb, w1.z, acc1q1.z); acc1q1.w = fmaf(xb, w1.w, acc1q1.w);
      acc1q2.x = fmaf(xb, w2.x, acc1q2.x); acc1q2.y = fmaf(xb, w2.y, acc1q2.y);
      acc1q2.z = fmaf(xb, w2.z, acc1q2.z); acc1q2.w = fmaf(xb, w2.w, acc1q2.w);
      acc1q3.x = fmaf(xb, w3.x, acc1q3.x); acc1q3.y = fmaf(xb, w3.y, acc1q3.y);
      acc1q3.z = fmaf(xb, w3.z, acc1q3.z); acc1q3.w = fmaf(xb, w3.w, acc1q3.w);
    }
  }

#pragma unroll
  for (int q = 0; q < 4; ++q) {
    int col = j0 + 32 * q;
    float4 b4 = *(const float4*)(bias + col);
    float4 a4 = *(const float4*)(pa + col);
    float4 aq0 = (q == 0) ? acc0q0 : (q == 1) ? acc0q1 : (q == 2) ? acc0q2 : acc0q3;
    float4 aq1 = (q == 0) ? acc1q0 : (q == 1) ? acc1q1 : (q == 2) ? acc1q2 : acc1q3;
    int ra = row0 + ia, rb = row0 + ib;
    if (ra < NN) {
      float4 v;
      v.x = aq0.x + b4.x; v.y = aq0.y + b4.y; v.z = aq0.z + b4.z; v.w = aq0.w + b4.w;
      v.x = v.x >= 0.f ? v.x : a4.x * v.x;
      v.y = v.y >= 0.f ? v.y : a4.y * v.y;
      v.z = v.z >= 0.f ? v.z : a4.z * v.z;
      v.w = v.w >= 0.f ? v.w : a4.w * v.w;
      if (do_post) { float ps = postscale[ra]; v.x *= ps; v.y *= ps; v.z *= ps; v.w *= ps; }
      *(float4*)(out + ra * FF + col) = v;
    }
    if (rb < NN) {
      float4 v;
      v.x = aq1.x + b4.x; v.y = aq1.y + b4.y; v.z = aq1.z + b4.z; v.w = aq1.w + b4.w;
      v.x = v.x >= 0.f ? v.x : a4.x * v.x;
      v.y = v.y >= 0.f ? v.y : a4.y * v.y;
      v.z = v.z >= 0.f ? v.z : a4.z * v.z;
      v.w = v.w >= 0.f ? v.w : a4.w * v.w;
      if (do_post) { float ps = postscale[rb]; v.x *= ps; v.y *= ps; v.z *= ps; v.w *= ps; }
      *(float4*)(out + rb * FF + col) = v;
    }
  }
}

// ---------------------------------------------------------------- launch
extern "C" void kernel_launch(void* const* d_in, const int* in_sizes, int n_in,
                              void* d_out, int out_size, void* d_ws, size_t ws_size,
                              hipStream_t stream) {
  const float* features = (const float*)d_in[0];
  const int*   ei       = (const int*)d_in[1];   // [2][E], int32
  const float* W1       = (const float*)d_in[2];
  const float* b1       = (const float*)d_in[3];
  const float* W2       = (const float*)d_in[4];
  const float* b2       = (const float*)d_in[5];
  const float* pa       = (const float*)d_in[6];
  float* out = (float*)d_out;

  char* ws = (char*)d_ws;
  size_t off = 0;
  auto alloc = [&](size_t bytes) -> void* {
    void* p = ws + off;
    off += (bytes + 255) & ~(size_t)255;
    return p;
  };
  int*   deg     = (int*)alloc((size_t)2 * NN * 4);
  int*   deg_out = deg;
  int*   deg_in  = deg + NN;
  float* dout_is = (float*)alloc((size_t)NN * 4);
  float* din_is  = (float*)alloc((size_t)NN * 4);
  int*   offs    = (int*)alloc((size_t)(NN + 1) * 4);
  int*   cursor  = (int*)alloc((size_t)NN * 4);
  int*   csr_src = (int*)alloc((size_t)EE * 4);
  float* tmp     = (float*)alloc((size_t)NN * FF * 4);

  hipMemsetAsync(deg, 0, (size_t)2 * NN * 4, stream);

  k_degrees<<<EE / 4 / 256, 256, 0, stream>>>(ei, deg_out, deg_in);            // 3125 blocks
  k_scales<<<(NN + 255) / 256, 256, 0, stream>>>(deg_out, deg_in, dout_is, din_is);
  k_scan<<<1, 1024, 0, stream>>>(deg_in, offs, cursor);
  k_scatter<<<EE / 4 / 256, 256, 0, stream>>>(ei, cursor, csr_src);            // 3125 blocks

  // layer 1: prescale features -> out ; agg(out) -> tmp ; gemm -> out (h1 * dout_is)
  k_prescale<<<(NN * FF / 4 + 255) / 256, 256, 0, stream>>>(features, dout_is, out);
  k_agg<<<NN / 4, 256, 0, stream>>>(out, din_is, offs, csr_src, tmp);
  k_gemm<<<(NN + 63) / 64, 256, 0, stream>>>(tmp, W1, b1, pa, dout_is, 1, out);

  // layer 2: agg(out) -> tmp ; gemm -> out (final)
  k_agg<<<NN / 4, 256, 0, stream>>>(out, din_is, offs, csr_src, tmp);
  k_gemm<<<(NN + 63) / 64, 256, 0, stream>>>(tmp, W2, b2, pa, dout_is, 0, out);
}

// Round 3
// 1141.573 us; speedup vs baseline: 1.1669x; 1.1669x over previous
//
#include <hip/hip_runtime.h>
#include <hip/hip_fp16.h>

#define NN 100000
#define EE 3200000
#define FF 128

// ---------------------------------------------------------------- degrees
__global__ __launch_bounds__(256) void k_degrees(const int* __restrict__ ei,
                                                 int* __restrict__ deg_out,
                                                 int* __restrict__ deg_in) {
  int t = blockIdx.x * blockDim.x + threadIdx.x;
  int e = t * 4;
  if (e >= EE) return;
  int4 s = *(const int4*)(ei + e);
  int4 d = *(const int4*)(ei + EE + e);
  atomicAdd(&deg_out[s.x], 1);
  atomicAdd(&deg_out[s.y], 1);
  atomicAdd(&deg_out[s.z], 1);
  atomicAdd(&deg_out[s.w], 1);
  atomicAdd(&deg_in[d.x], 1);
  atomicAdd(&deg_in[d.y], 1);
  atomicAdd(&deg_in[d.z], 1);
  atomicAdd(&deg_in[d.w], 1);
}

// ---------------------------------------------------------------- norm scales
__global__ __launch_bounds__(256) void k_scales(const int* __restrict__ deg_out,
                                                const int* __restrict__ deg_in,
                                                float* __restrict__ dout_is,
                                                float* __restrict__ din_is) {
  int i = blockIdx.x * blockDim.x + threadIdx.x;
  if (i < NN) {
    int doo = deg_out[i]; if (doo < 1) doo = 1;
    int dii = deg_in[i];  if (dii < 1) dii = 1;
    dout_is[i] = rsqrtf((float)doo);
    din_is[i]  = rsqrtf((float)dii);
  }
}

// ---------------------------------------------------------------- exclusive scan (single block)
__global__ __launch_bounds__(1024) void k_scan(const int* __restrict__ deg,
                                               int* __restrict__ offs,
                                               int* __restrict__ cursor) {
  __shared__ int sums[1024];
  const int T = 1024;
  const int per = (NN + T - 1) / T;
  int tid = threadIdx.x;
  int start = tid * per;
  int end = start + per; if (end > NN) end = NN;
  if (start > NN) start = NN;
  int s = 0;
  for (int i = start; i < end; ++i) s += deg[i];
  sums[tid] = s;
  __syncthreads();
  for (int off = 1; off < T; off <<= 1) {
    int v = (tid >= off) ? sums[tid - off] : 0;
    __syncthreads();
    sums[tid] += v;
    __syncthreads();
  }
  int run = (tid == 0) ? 0 : sums[tid - 1];
  for (int i = start; i < end; ++i) {
    offs[i] = run; cursor[i] = run; run += deg[i];
  }
  if (tid == T - 1) offs[NN] = run;
}

// ---------------------------------------------------------------- CSR scatter
__global__ __launch_bounds__(256) void k_scatter(const int* __restrict__ ei,
                                                 int* __restrict__ cursor,
                                                 int* __restrict__ csr_src) {
  int t = blockIdx.x * blockDim.x + threadIdx.x;
  int e = t * 4;
  if (e >= EE) return;
  int4 s = *(const int4*)(ei + e);
  int4 d = *(const int4*)(ei + EE + e);
  int p0 = atomicAdd(&cursor[d.x], 1);
  int p1 = atomicAdd(&cursor[d.y], 1);
  int p2 = atomicAdd(&cursor[d.z], 1);
  int p3 = atomicAdd(&cursor[d.w], 1);
  csr_src[p0] = s.x;
  csr_src[p1] = s.y;
  csr_src[p2] = s.z;
  csr_src[p3] = s.w;
}

// ---------------------------------------------------------------- prescale to fp16
// xh[i][:] = (half)(x[i][:] * dout_is[i]); one thread = 4 elements
__global__ __launch_bounds__(256) void k_prescale_h(const float* __restrict__ x,
                                                    const float* __restrict__ dout_is,
                                                    __half* __restrict__ xh) {
  int t = blockIdx.x * blockDim.x + threadIdx.x;
  if (t >= NN * (FF / 4)) return;
  int node = t >> 5;
  float sc = dout_is[node];
  float4 v = ((const float4*)x)[t];
  union { __half2 h[2]; uint2 u; } p;
  p.h[0] = __floats2half2_rn(v.x * sc, v.y * sc);
  p.h[1] = __floats2half2_rn(v.z * sc, v.w * sc);
  ((uint2*)xh)[t] = p.u;
}

// ---------------------------------------------------------------- pull aggregation (fp16 gather, fp32 accum)
// out[i] = din_is[i] * sum_{e in in(i)} xh[src(e)]
// one wave per node; lane owns 2 cols via one half2 (4B) -> 256B/edge
__global__ __launch_bounds__(256) void k_agg(const __half* __restrict__ xh,
                                             const float* __restrict__ din_is,
                                             const int* __restrict__ offs,
                                             const int* __restrict__ csr_src,
                                             float* __restrict__ out) {
  int gid = blockIdx.x * blockDim.x + threadIdx.x;
  int node = gid >> 6;
  int lane = threadIdx.x & 63;
  if (node >= NN) return;
  int beg = offs[node], end = offs[node + 1];
  float ax = 0.f, ay = 0.f, bx = 0.f, by = 0.f;
  int e = beg;
  for (; e < end && (e & 3); ++e) {
    int s = csr_src[e];
    float2 v = __half22float2(((const __half2*)(xh + (size_t)s * FF))[lane]);
    ax += v.x; ay += v.y;
  }
  for (; e + 8 <= end; e += 8) {
    int4 i0 = *(const int4*)(csr_src + e);
    int4 i1 = *(const int4*)(csr_src + e + 4);
    float2 v0 = __half22float2(((const __half2*)(xh + (size_t)i0.x * FF))[lane]);
    float2 v1 = __half22float2(((const __half2*)(xh + (size_t)i0.y * FF))[lane]);
    float2 v2 = __half22float2(((const __half2*)(xh + (size_t)i0.z * FF))[lane]);
    float2 v3 = __half22float2(((const __half2*)(xh + (size_t)i0.w * FF))[lane]);
    float2 v4 = __half22float2(((const __half2*)(xh + (size_t)i1.x * FF))[lane]);
    float2 v5 = __half22float2(((const __half2*)(xh + (size_t)i1.y * FF))[lane]);
    float2 v6 = __half22float2(((const __half2*)(xh + (size_t)i1.z * FF))[lane]);
    float2 v7 = __half22float2(((const __half2*)(xh + (size_t)i1.w * FF))[lane]);
    ax += v0.x; ay += v0.y; bx += v1.x; by += v1.y;
    ax += v2.x; ay += v2.y; bx += v3.x; by += v3.y;
    ax += v4.x; ay += v4.y; bx += v5.x; by += v5.y;
    ax += v6.x; ay += v6.y; bx += v7.x; by += v7.y;
  }
  for (; e < end; ++e) {
    int s = csr_src[e];
    float2 v = __half22float2(((const __half2*)(xh + (size_t)s * FF))[lane]);
    ax += v.x; ay += v.y;
  }
  float di = din_is[node];
  float2 r; r.x = (ax + bx) * di; r.y = (ay + by) * di;
  *(float2*)(out + node * FF + lane * 2) = r;
}

// ---------------------------------------------------------------- GEMM + bias + PReLU
// out_half=1: write (half)(result * postscale[row]) to outh  (layer-2 input)
// out_half=0: write fp32 result to outf                      (final output)
__global__ __launch_bounds__(256) void k_gemm(const float* __restrict__ X,
                                              const float* __restrict__ W,
                                              const float* __restrict__ bias,
                                              const float* __restrict__ pa,
                                              const float* __restrict__ postscale,
                                              int out_half,
                                              float* __restrict__ outf,
                                              __half* __restrict__ outh) {
  __shared__ float Xs[64][FF + 1];
  __shared__ float Wt[32][FF];
  int tid = threadIdx.x;
  int row0 = blockIdx.x * 64;

  for (int t = tid; t < 64 * (FF / 4); t += 256) {
    int r = t >> 5;
    int c4 = (t & 31) * 4;
    int row = row0 + r;
    float4 v = make_float4(0.f, 0.f, 0.f, 0.f);
    if (row < NN) v = *(const float4*)(X + row * FF + c4);
    Xs[r][c4 + 0] = v.x; Xs[r][c4 + 1] = v.y; Xs[r][c4 + 2] = v.z; Xs[r][c4 + 3] = v.w;
  }

  int rp = tid >> 3;
  int ia = rp * 2, ib = ia + 1;
  int j0 = (tid & 7) * 4;

  float4 acc0q0 = make_float4(0,0,0,0), acc0q1 = acc0q0, acc0q2 = acc0q0, acc0q3 = acc0q0;
  float4 acc1q0 = acc0q0, acc1q1 = acc0q0, acc1q2 = acc0q0, acc1q3 = acc0q0;

  for (int kt = 0; kt < 4; ++kt) {
    __syncthreads();
    {
      const float4* W4 = (const float4*)(W + kt * 32 * FF);
      float4* Wt4 = (float4*)(&Wt[0][0]);
      for (int t = tid; t < 32 * FF / 4; t += 256) Wt4[t] = W4[t];
    }
    __syncthreads();
#pragma unroll
    for (int k = 0; k < 32; ++k) {
      float xa = Xs[ia][kt * 32 + k];
      float xb = Xs[ib][kt * 32 + k];
      float4 w0 = *(const float4*)(&Wt[k][j0 + 0]);
      float4 w1 = *(const float4*)(&Wt[k][j0 + 32]);
      float4 w2 = *(const float4*)(&Wt[k][j0 + 64]);
      float4 w3 = *(const float4*)(&Wt[k][j0 + 96]);
      acc0q0.x = fmaf(xa, w0.x, acc0q0.x); acc0q0.y = fmaf(xa, w0.y, acc0q0.y);
      acc0q0.z = fmaf(xa, w0.z, acc0q0.z); acc0q0.w = fmaf(xa, w0.w, acc0q0.w);
      acc0q1.x = fmaf(xa, w1.x, acc0q1.x); acc0q1.y = fmaf(xa, w1.y, acc0q1.y);
      acc0q1.z = fmaf(xa, w1.z, acc0q1.z); acc0q1.w = fmaf(xa, w1.w, acc0q1.w);
      acc0q2.x = fmaf(xa, w2.x, acc0q2.x); acc0q2.y = fmaf(xa, w2.y, acc0q2.y);
      acc0q2.z = fmaf(xa, w2.z, acc0q2.z); acc0q2.w = fmaf(xa, w2.w, acc0q2.w);
      acc0q3.x = fmaf(xa, w3.x, acc0q3.x); acc0q3.y = fmaf(xa, w3.y, acc0q3.y);
      acc0q3.z = fmaf(xa, w3.z, acc0q3.z); acc0q3.w = fmaf(xa, w3.w, acc0q3.w);
      acc1q0.x = fmaf(xb, w0.x, acc1q0.x); acc1q0.y = fmaf(xb, w0.y, acc1q0.y);
      acc1q0.z = fmaf(xb, w0.z, acc1q0.z); acc1q0.w = fmaf(xb, w0.w, acc1q0.w);
      acc1q1.x = fmaf(xb, w1.x, acc1q1.x); acc1q1.y = fmaf(xb, w1.y, acc1q1.y);
      acc1q1.z = fmaf(xb, w1.z, acc1q1.z); acc1q1.w = fmaf(xb, w1.w, acc1q1.w);
      acc1q2.x = fmaf(xb, w2.x, acc1q2.x); acc1q2.y = fmaf(xb, w2.y, acc1q2.y);
      acc1q2.z = fmaf(xb, w2.z, acc1q2.z); acc1q2.w = fmaf(xb, w2.w, acc1q2.w);
      acc1q3.x = fmaf(xb, w3.x, acc1q3.x); acc1q3.y = fmaf(xb, w3.y, acc1q3.y);
      acc1q3.z = fmaf(xb, w3.z, acc1q3.z); acc1q3.w = fmaf(xb, w3.w, acc1q3.w);
    }
  }

#pragma unroll
  for (int q = 0; q < 4; ++q) {
    int col = j0 + 32 * q;
    float4 b4 = *(const float4*)(bias + col);
    float4 a4 = *(const float4*)(pa + col);
    float4 aq0 = (q == 0) ? acc0q0 : (q == 1) ? acc0q1 : (q == 2) ? acc0q2 : acc0q3;
    float4 aq1 = (q == 0) ? acc1q0 : (q == 1) ? acc1q1 : (q == 2) ? acc1q2 : acc1q3;
    int ra = row0 + ia, rb = row0 + ib;
#pragma unroll
    for (int h = 0; h < 2; ++h) {
      int row = h ? rb : ra;
      float4 aq = h ? aq1 : aq0;
      if (row < NN) {
        float4 v;
        v.x = aq.x + b4.x; v.y = aq.y + b4.y; v.z = aq.z + b4.z; v.w = aq.w + b4.w;
        v.x = v.x >= 0.f ? v.x : a4.x * v.x;
        v.y = v.y >= 0.f ? v.y : a4.y * v.y;
        v.z = v.z >= 0.f ? v.z : a4.z * v.z;
        v.w = v.w >= 0.f ? v.w : a4.w * v.w;
        if (out_half) {
          float ps = postscale[row];
          union { __half2 hh[2]; uint2 u; } p;
          p.hh[0] = __floats2half2_rn(v.x * ps, v.y * ps);
          p.hh[1] = __floats2half2_rn(v.z * ps, v.w * ps);
          *(uint2*)(outh + (size_t)row * FF + col) = p.u;
        } else {
          *(float4*)(outf + (size_t)row * FF + col) = v;
        }
      }
    }
  }
}

// ---------------------------------------------------------------- launch
extern "C" void kernel_launch(void* const* d_in, const int* in_sizes, int n_in,
                              void* d_out, int out_size, void* d_ws, size_t ws_size,
                              hipStream_t stream) {
  const float* features = (const float*)d_in[0];
  const int*   ei       = (const int*)d_in[1];
  const float* W1       = (const float*)d_in[2];
  const float* b1       = (const float*)d_in[3];
  const float* W2       = (const float*)d_in[4];
  const float* b2       = (const float*)d_in[5];
  const float* pa       = (const float*)d_in[6];
  float* out = (float*)d_out;

  char* ws = (char*)d_ws;
  size_t off = 0;
  auto alloc = [&](size_t bytes) -> void* {
    void* p = ws + off;
    off += (bytes + 255) & ~(size_t)255;
    return p;
  };
  int*    deg     = (int*)alloc((size_t)2 * NN * 4);
  int*    deg_out = deg;
  int*    deg_in  = deg + NN;
  float*  dout_is = (float*)alloc((size_t)NN * 4);
  float*  din_is  = (float*)alloc((size_t)NN * 4);
  int*    offs    = (int*)alloc((size_t)(NN + 1) * 4);
  int*    cursor  = (int*)alloc((size_t)NN * 4);
  int*    csr_src = (int*)alloc((size_t)EE * 4);
  float*  tmp     = (float*)alloc((size_t)NN * FF * 4);
  __half* xh      = (__half*)alloc((size_t)NN * FF * 2);   // prescaled gather buffer (both layers)

  hipMemsetAsync(deg, 0, (size_t)2 * NN * 4, stream);

  k_degrees<<<EE / 4 / 256, 256, 0, stream>>>(ei, deg_out, deg_in);
  k_scales<<<(NN + 255) / 256, 256, 0, stream>>>(deg_out, deg_in, dout_is, din_is);
  k_scan<<<1, 1024, 0, stream>>>(deg_in, offs, cursor);
  k_scatter<<<EE / 4 / 256, 256, 0, stream>>>(ei, cursor, csr_src);

  // layer 1: prescale->xh(half) ; agg(xh)->tmp ; gemm -> xh(half, *dout_is)
  k_prescale_h<<<(NN * FF / 4 + 255) / 256, 256, 0, stream>>>(features, dout_is, xh);
  k_agg<<<NN / 4, 256, 0, stream>>>(xh, din_is, offs, csr_src, tmp);
  k_gemm<<<(NN + 63) / 64, 256, 0, stream>>>(tmp, W1, b1, pa, dout_is, 1, nullptr, xh);

  // layer 2: agg(xh)->tmp ; gemm -> out(fp32)
  k_agg<<<NN / 4, 256, 0, stream>>>(xh, din_is, offs, csr_src, tmp);
  k_gemm<<<(NN + 63) / 64, 256, 0, stream>>>(tmp, W2, b2, pa, nullptr, 0, out, nullptr);
}

// Round 4
// 634.314 us; speedup vs baseline: 2.1000x; 1.7997x over previous
//
#include <hip/hip_runtime.h>
#include <hip/hip_fp16.h>

#define NN 100000
#define EE 3200000
#define FF 128

#define NBUK 98            // ceil(NN / 1024); bucket = dst >> 10
#define CH_A 8192          // edges per Phase-A block
#define NB_A ((EE + CH_A - 1) / CH_A)   // 391

// ---------------------------------------------------------------- deg_out histogram (src)
__global__ __launch_bounds__(256) void k_degout(const int* __restrict__ ei,
                                                int* __restrict__ deg_out) {
  int t = blockIdx.x * blockDim.x + threadIdx.x;
  int e = t * 4;
  if (e >= EE) return;
  int4 s = *(const int4*)(ei + e);
  atomicAdd(&deg_out[s.x], 1);
  atomicAdd(&deg_out[s.y], 1);
  atomicAdd(&deg_out[s.z], 1);
  atomicAdd(&deg_out[s.w], 1);
}

// ---------------------------------------------------------------- Phase A1: bucket totals
__global__ __launch_bounds__(256) void k_bukhist(const int* __restrict__ dst,
                                                 int* __restrict__ bucket_totals) {
  __shared__ int h[NBUK];
  int tid = threadIdx.x;
  if (tid < NBUK) h[tid] = 0;
  __syncthreads();
  int base = blockIdx.x * CH_A;
#pragma unroll
  for (int k = 0; k < CH_A / 256; ++k) {
    int e = base + k * 256 + tid;
    if (e < EE) atomicAdd(&h[dst[e] >> 10], 1);
  }
  __syncthreads();
  if (tid < NBUK && h[tid] > 0) atomicAdd(&bucket_totals[tid], h[tid]);
}

// ---------------------------------------------------------------- Phase A2: tiny scan
__global__ __launch_bounds__(64) void k_bukscan(const int* __restrict__ bucket_totals,
                                                int* __restrict__ bucket_base,
                                                int* __restrict__ bucket_cursor,
                                                int* __restrict__ offs) {
  if (threadIdx.x == 0) {
    int run = 0;
    for (int b = 0; b < NBUK; ++b) {
      bucket_base[b] = run;
      bucket_cursor[b] = run;
      run += bucket_totals[b];
    }
    bucket_base[NBUK] = run;   // == EE
    offs[NN] = run;
  }
}

// ---------------------------------------------------------------- Phase A3: bin pairs by dst-bucket
__global__ __launch_bounds__(256) void k_bin(const int* __restrict__ ei,
                                             int* __restrict__ bucket_cursor,
                                             int2* __restrict__ binned) {
  __shared__ int h[NBUK];
  __shared__ int c[NBUK];
  int tid = threadIdx.x;
  if (tid < NBUK) h[tid] = 0;
  __syncthreads();
  int base = blockIdx.x * CH_A;
  const int* dst = ei + EE;
#pragma unroll
  for (int k = 0; k < CH_A / 256; ++k) {
    int e = base + k * 256 + tid;
    if (e < EE) atomicAdd(&h[dst[e] >> 10], 1);
  }
  __syncthreads();
  if (tid < NBUK && h[tid] > 0) c[tid] = atomicAdd(&bucket_cursor[tid], h[tid]);
  __syncthreads();
#pragma unroll
  for (int k = 0; k < CH_A / 256; ++k) {
    int e = base + k * 256 + tid;
    if (e < EE) {
      int s = ei[e];
      int d = dst[e];
      int pos = atomicAdd(&c[d >> 10], 1);
      binned[pos] = make_int2(s, d);
    }
  }
}

// ---------------------------------------------------------------- Phase B: per-bucket CSR finalize
// one block per bucket: LDS hist (=deg_in) -> LDS scan (=offs) -> rank scatter (csr_src)
__global__ __launch_bounds__(1024) void k_csr(const int2* __restrict__ binned,
                                              const int* __restrict__ bucket_base,
                                              int* __restrict__ offs,
                                              int* __restrict__ deg_in,
                                              int* __restrict__ csr_src) {
  __shared__ int h[1024];
  __shared__ int sa[1024];
  __shared__ int cur[1024];
  int tid = threadIdx.x;
  int b = blockIdx.x;
  int dst0 = b << 10;
  int beg = bucket_base[b];
  int cnt = bucket_base[b + 1] - beg;

  h[tid] = 0;
  __syncthreads();
  for (int t = tid; t < cnt; t += 1024) {
    int d = binned[beg + t].y;
    atomicAdd(&h[d - dst0], 1);
  }
  __syncthreads();
  sa[tid] = h[tid];
  __syncthreads();
  for (int off = 1; off < 1024; off <<= 1) {
    int v = (tid >= off) ? sa[tid - off] : 0;
    __syncthreads();
    sa[tid] += v;
    __syncthreads();
  }
  int excl = sa[tid] - h[tid];
  cur[tid] = beg + excl;
  int node = dst0 + tid;
  if (node < NN) {
    offs[node] = beg + excl;
    deg_in[node] = h[tid];
  }
  __syncthreads();
  for (int t = tid; t < cnt; t += 1024) {
    int2 p = binned[beg + t];
    int pos = atomicAdd(&cur[p.y - dst0], 1);
    csr_src[pos] = p.x;
  }
}

// ---------------------------------------------------------------- norm scales
__global__ __launch_bounds__(256) void k_scales(const int* __restrict__ deg_out,
                                                const int* __restrict__ deg_in,
                                                float* __restrict__ dout_is,
                                                float* __restrict__ din_is) {
  int i = blockIdx.x * blockDim.x + threadIdx.x;
  if (i < NN) {
    int doo = deg_out[i]; if (doo < 1) doo = 1;
    int dii = deg_in[i];  if (dii < 1) dii = 1;
    dout_is[i] = rsqrtf((float)doo);
    din_is[i]  = rsqrtf((float)dii);
  }
}

// ---------------------------------------------------------------- prescale to fp16
__global__ __launch_bounds__(256) void k_prescale_h(const float* __restrict__ x,
                                                    const float* __restrict__ dout_is,
                                                    __half* __restrict__ xh) {
  int t = blockIdx.x * blockDim.x + threadIdx.x;
  if (t >= NN * (FF / 4)) return;
  int node = t >> 5;
  float sc = dout_is[node];
  float4 v = ((const float4*)x)[t];
  union { __half2 h[2]; uint2 u; } p;
  p.h[0] = __floats2half2_rn(v.x * sc, v.y * sc);
  p.h[1] = __floats2half2_rn(v.z * sc, v.w * sc);
  ((uint2*)xh)[t] = p.u;
}

// ---------------------------------------------------------------- pull aggregation (fp16 gather, fp32 accum)
__global__ __launch_bounds__(256) void k_agg(const __half* __restrict__ xh,
                                             const float* __restrict__ din_is,
                                             const int* __restrict__ offs,
                                             const int* __restrict__ csr_src,
                                             float* __restrict__ out) {
  int gid = blockIdx.x * blockDim.x + threadIdx.x;
  int node = gid >> 6;
  int lane = threadIdx.x & 63;
  if (node >= NN) return;
  int beg = offs[node], end = offs[node + 1];
  float ax = 0.f, ay = 0.f, bx = 0.f, by = 0.f;
  int e = beg;
  for (; e < end && (e & 3); ++e) {
    int s = csr_src[e];
    float2 v = __half22float2(((const __half2*)(xh + (size_t)s * FF))[lane]);
    ax += v.x; ay += v.y;
  }
  for (; e + 8 <= end; e += 8) {
    int4 i0 = *(const int4*)(csr_src + e);
    int4 i1 = *(const int4*)(csr_src + e + 4);
    float2 v0 = __half22float2(((const __half2*)(xh + (size_t)i0.x * FF))[lane]);
    float2 v1 = __half22float2(((const __half2*)(xh + (size_t)i0.y * FF))[lane]);
    float2 v2 = __half22float2(((const __half2*)(xh + (size_t)i0.z * FF))[lane]);
    float2 v3 = __half22float2(((const __half2*)(xh + (size_t)i0.w * FF))[lane]);
    float2 v4 = __half22float2(((const __half2*)(xh + (size_t)i1.x * FF))[lane]);
    float2 v5 = __half22float2(((const __half2*)(xh + (size_t)i1.y * FF))[lane]);
    float2 v6 = __half22float2(((const __half2*)(xh + (size_t)i1.z * FF))[lane]);
    float2 v7 = __half22float2(((const __half2*)(xh + (size_t)i1.w * FF))[lane]);
    ax += v0.x; ay += v0.y; bx += v1.x; by += v1.y;
    ax += v2.x; ay += v2.y; bx += v3.x; by += v3.y;
    ax += v4.x; ay += v4.y; bx += v5.x; by += v5.y;
    ax += v6.x; ay += v6.y; bx += v7.x; by += v7.y;
  }
  for (; e < end; ++e) {
    int s = csr_src[e];
    float2 v = __half22float2(((const __half2*)(xh + (size_t)s * FF))[lane]);
    ax += v.x; ay += v.y;
  }
  float di = din_is[node];
  float2 r; r.x = (ax + bx) * di; r.y = (ay + by) * di;
  *(float2*)(out + node * FF + lane * 2) = r;
}

// ---------------------------------------------------------------- GEMM + bias + PReLU
__global__ __launch_bounds__(256) void k_gemm(const float* __restrict__ X,
                                              const float* __restrict__ W,
                                              const float* __restrict__ bias,
                                              const float* __restrict__ pa,
                                              const float* __restrict__ postscale,
                                              int out_half,
                                              float* __restrict__ outf,
                                              __half* __restrict__ outh) {
  __shared__ float Xs[64][FF + 1];
  __shared__ float Wt[32][FF];
  int tid = threadIdx.x;
  int row0 = blockIdx.x * 64;

  for (int t = tid; t < 64 * (FF / 4); t += 256) {
    int r = t >> 5;
    int c4 = (t & 31) * 4;
    int row = row0 + r;
    float4 v = make_float4(0.f, 0.f, 0.f, 0.f);
    if (row < NN) v = *(const float4*)(X + row * FF + c4);
    Xs[r][c4 + 0] = v.x; Xs[r][c4 + 1] = v.y; Xs[r][c4 + 2] = v.z; Xs[r][c4 + 3] = v.w;
  }

  int rp = tid >> 3;
  int ia = rp * 2, ib = ia + 1;
  int j0 = (tid & 7) * 4;

  float4 acc0q0 = make_float4(0,0,0,0), acc0q1 = acc0q0, acc0q2 = acc0q0, acc0q3 = acc0q0;
  float4 acc1q0 = acc0q0, acc1q1 = acc0q0, acc1q2 = acc0q0, acc1q3 = acc0q0;

  for (int kt = 0; kt < 4; ++kt) {
    __syncthreads();
    {
      const float4* W4 = (const float4*)(W + kt * 32 * FF);
      float4* Wt4 = (float4*)(&Wt[0][0]);
      for (int t = tid; t < 32 * FF / 4; t += 256) Wt4[t] = W4[t];
    }
    __syncthreads();
#pragma unroll
    for (int k = 0; k < 32; ++k) {
      float xa = Xs[ia][kt * 32 + k];
      float xb = Xs[ib][kt * 32 + k];
      float4 w0 = *(const float4*)(&Wt[k][j0 + 0]);
      float4 w1 = *(const float4*)(&Wt[k][j0 + 32]);
      float4 w2 = *(const float4*)(&Wt[k][j0 + 64]);
      float4 w3 = *(const float4*)(&Wt[k][j0 + 96]);
      acc0q0.x = fmaf(xa, w0.x, acc0q0.x); acc0q0.y = fmaf(xa, w0.y, acc0q0.y);
      acc0q0.z = fmaf(xa, w0.z, acc0q0.z); acc0q0.w = fmaf(xa, w0.w, acc0q0.w);
      acc0q1.x = fmaf(xa, w1.x, acc0q1.x); acc0q1.y = fmaf(xa, w1.y, acc0q1.y);
      acc0q1.z = fmaf(xa, w1.z, acc0q1.z); acc0q1.w = fmaf(xa, w1.w, acc0q1.w);
      acc0q2.x = fmaf(xa, w2.x, acc0q2.x); acc0q2.y = fmaf(xa, w2.y, acc0q2.y);
      acc0q2.z = fmaf(xa, w2.z, acc0q2.z); acc0q2.w = fmaf(xa, w2.w, acc0q2.w);
      acc0q3.x = fmaf(xa, w3.x, acc0q3.x); acc0q3.y = fmaf(xa, w3.y, acc0q3.y);
      acc0q3.z = fmaf(xa, w3.z, acc0q3.z); acc0q3.w = fmaf(xa, w3.w, acc0q3.w);
      acc1q0.x = fmaf(xb, w0.x, acc1q0.x); acc1q0.y = fmaf(xb, w0.y, acc1q0.y);
      acc1q0.z = fmaf(xb, w0.z, acc1q0.z); acc1q0.w = fmaf(xb, w0.w, acc1q0.w);
      acc1q1.x = fmaf(xb, w1.x, acc1q1.x); acc1q1.y = fmaf(xb, w1.y, acc1q1.y);
      acc1q1.z = fmaf(xb, w1.z, acc1q1.z); acc1q1.w = fmaf(xb, w1.w, acc1q1.w);
      acc1q2.x = fmaf(xb, w2.x, acc1q2.x); acc1q2.y = fmaf(xb, w2.y, acc1q2.y);
      acc1q2.z = fmaf(xb, w2.z, acc1q2.z); acc1q2.w = fmaf(xb, w2.w, acc1q2.w);
      acc1q3.x = fmaf(xb, w3.x, acc1q3.x); acc1q3.y = fmaf(xb, w3.y, acc1q3.y);
      acc1q3.z = fmaf(xb, w3.z, acc1q3.z); acc1q3.w = fmaf(xb, w3.w, acc1q3.w);
    }
  }

#pragma unroll
  for (int q = 0; q < 4; ++q) {
    int col = j0 + 32 * q;
    float4 b4 = *(const float4*)(bias + col);
    float4 a4 = *(const float4*)(pa + col);
    float4 aq0 = (q == 0) ? acc0q0 : (q == 1) ? acc0q1 : (q == 2) ? acc0q2 : acc0q3;
    float4 aq1 = (q == 0) ? acc1q0 : (q == 1) ? acc1q1 : (q == 2) ? acc1q2 : acc1q3;
    int ra = row0 + ia, rb = row0 + ib;
#pragma unroll
    for (int h = 0; h < 2; ++h) {
      int row = h ? rb : ia + row0 + 1 - 1 + (h ? 1 : 0); // placeholder avoided below
      row = h ? rb : ra;
      float4 aq = h ? aq1 : aq0;
      if (row < NN) {
        float4 v;
        v.x = aq.x + b4.x; v.y = aq.y + b4.y; v.z = aq.z + b4.z; v.w = aq.w + b4.w;
        v.x = v.x >= 0.f ? v.x : a4.x * v.x;
        v.y = v.y >= 0.f ? v.y : a4.y * v.y;
        v.z = v.z >= 0.f ? v.z : a4.z * v.z;
        v.w = v.w >= 0.f ? v.w : a4.w * v.w;
        if (out_half) {
          float ps = postscale[row];
          union { __half2 hh[2]; uint2 u; } p;
          p.hh[0] = __floats2half2_rn(v.x * ps, v.y * ps);
          p.hh[1] = __floats2half2_rn(v.z * ps, v.w * ps);
          *(uint2*)(outh + (size_t)row * FF + col) = p.u;
        } else {
          *(float4*)(outf + (size_t)row * FF + col) = v;
        }
      }
    }
  }
}

// ---------------------------------------------------------------- launch
extern "C" void kernel_launch(void* const* d_in, const int* in_sizes, int n_in,
                              void* d_out, int out_size, void* d_ws, size_t ws_size,
                              hipStream_t stream) {
  const float* features = (const float*)d_in[0];
  const int*   ei       = (const int*)d_in[1];
  const float* W1       = (const float*)d_in[2];
  const float* b1       = (const float*)d_in[3];
  const float* W2       = (const float*)d_in[4];
  const float* b2       = (const float*)d_in[5];
  const float* pa       = (const float*)d_in[6];
  float* out = (float*)d_out;

  char* ws = (char*)d_ws;
  size_t off = 0;
  auto alloc = [&](size_t bytes) -> void* {
    void* p = ws + off;
    off += (bytes + 255) & ~(size_t)255;
    return p;
  };
  // zeroed region: deg_out (NN) + bucket_totals (NBUK) contiguous
  int*    zreg          = (int*)alloc((size_t)(NN + NBUK) * 4);
  int*    deg_out       = zreg;
  int*    bucket_totals = zreg + NN;
  int*    deg_in        = (int*)alloc((size_t)NN * 4);
  float*  dout_is       = (float*)alloc((size_t)NN * 4);
  float*  din_is        = (float*)alloc((size_t)NN * 4);
  int*    offs          = (int*)alloc((size_t)(NN + 1) * 4);
  int*    bucket_base   = (int*)alloc((size_t)(NBUK + 1) * 4);
  int*    bucket_cursor = (int*)alloc((size_t)NBUK * 4);
  int*    csr_src       = (int*)alloc((size_t)EE * 4);
  float*  tmp           = (float*)alloc((size_t)NN * FF * 4);
  __half* xh            = (__half*)alloc((size_t)NN * FF * 2);
  int2*   binned        = (int2*)tmp;   // aliases tmp: binning done before aggs

  hipMemsetAsync(zreg, 0, (size_t)(NN + NBUK) * 4, stream);

  // CSR build (dst-binned, LDS-based)
  k_bukhist<<<NB_A, 256, 0, stream>>>(ei + EE, bucket_totals);
  k_bukscan<<<1, 64, 0, stream>>>(bucket_totals, bucket_base, bucket_cursor, offs);
  k_bin<<<NB_A, 256, 0, stream>>>(ei, bucket_cursor, binned);
  k_csr<<<NBUK, 1024, 0, stream>>>(binned, bucket_base, offs, deg_in, csr_src);

  // deg_out + scales
  k_degout<<<EE / 4 / 256, 256, 0, stream>>>(ei, deg_out);
  k_scales<<<(NN + 255) / 256, 256, 0, stream>>>(deg_out, deg_in, dout_is, din_is);

  // layer 1: prescale->xh(half) ; agg(xh)->tmp ; gemm -> xh(half, *dout_is)
  k_prescale_h<<<(NN * FF / 4 + 255) / 256, 256, 0, stream>>>(features, dout_is, xh);
  k_agg<<<NN / 4, 256, 0, stream>>>(xh, din_is, offs, csr_src, tmp);
  k_gemm<<<(NN + 63) / 64, 256, 0, stream>>>(tmp, W1, b1, pa, dout_is, 1, nullptr, xh);

  // layer 2: agg(xh)->tmp ; gemm -> out(fp32)
  k_agg<<<NN / 4, 256, 0, stream>>>(xh, din_is, offs, csr_src, tmp);
  k_gemm<<<(NN + 63) / 64, 256, 0, stream>>>(tmp, W2, b2, pa, nullptr, 0, out, nullptr);
}

// Round 5
// 541.670 us; speedup vs baseline: 2.4592x; 1.1710x over previous
//
#include <hip/hip_runtime.h>
#include <hip/hip_fp16.h>

#define NN 100000
#define EE 3200000
#define FF 128

#define NBUK 98            // ceil(NN / 1024); bucket = id >> 10
#define CH_A 8192          // edges per Phase-A block
#define NB_A ((EE + CH_A - 1) / CH_A)   // 391

// ---------------------------------------------------------------- Phase A1: dual bucket totals (dst + src)
__global__ __launch_bounds__(256) void k_bukhist2(const int* __restrict__ ei,
                                                  int* __restrict__ dst_tot,
                                                  int* __restrict__ src_tot) {
  __shared__ int hd[NBUK];
  __shared__ int hs[NBUK];
  int tid = threadIdx.x;
  if (tid < NBUK) { hd[tid] = 0; hs[tid] = 0; }
  __syncthreads();
  int base = blockIdx.x * CH_A;
#pragma unroll
  for (int k = 0; k < CH_A / 256; ++k) {
    int e = base + k * 256 + tid;
    if (e < EE) {
      atomicAdd(&hs[ei[e] >> 10], 1);
      atomicAdd(&hd[ei[EE + e] >> 10], 1);
    }
  }
  __syncthreads();
  if (tid < NBUK) {
    if (hd[tid] > 0) atomicAdd(&dst_tot[tid], hd[tid]);
    if (hs[tid] > 0) atomicAdd(&src_tot[tid], hs[tid]);
  }
}

// ---------------------------------------------------------------- Phase A2: tiny scans
__global__ __launch_bounds__(64) void k_bukscan(const int* __restrict__ dst_tot,
                                                const int* __restrict__ src_tot,
                                                int* __restrict__ dbase,
                                                int* __restrict__ dcur,
                                                int* __restrict__ sbase,
                                                int* __restrict__ scur,
                                                int* __restrict__ offs) {
  if (threadIdx.x == 0) {
    int run = 0;
    for (int b = 0; b < NBUK; ++b) {
      dbase[b] = run; dcur[b] = run; run += dst_tot[b];
    }
    dbase[NBUK] = run;
    offs[NN] = run;
  }
  if (threadIdx.x == 1) {
    int run = 0;
    for (int b = 0; b < NBUK; ++b) {
      sbase[b] = run; scur[b] = run; run += src_tot[b];
    }
    sbase[NBUK] = run;
  }
}

// ---------------------------------------------------------------- Phase A3: bin pairs by dst-bucket + srcs by src-bucket
__global__ __launch_bounds__(256) void k_bin2(const int* __restrict__ ei,
                                              int* __restrict__ dcur_g,
                                              int* __restrict__ scur_g,
                                              int2* __restrict__ binned,
                                              int* __restrict__ src_binned) {
  __shared__ int hd[NBUK];
  __shared__ int hs[NBUK];
  __shared__ int cd[NBUK];
  __shared__ int cs[NBUK];
  int tid = threadIdx.x;
  if (tid < NBUK) { hd[tid] = 0; hs[tid] = 0; }
  __syncthreads();
  int base = blockIdx.x * CH_A;
  const int* dst = ei + EE;
#pragma unroll
  for (int k = 0; k < CH_A / 256; ++k) {
    int e = base + k * 256 + tid;
    if (e < EE) {
      atomicAdd(&hs[ei[e] >> 10], 1);
      atomicAdd(&hd[dst[e] >> 10], 1);
    }
  }
  __syncthreads();
  if (tid < NBUK) {
    cd[tid] = (hd[tid] > 0) ? atomicAdd(&dcur_g[tid], hd[tid]) : 0;
    cs[tid] = (hs[tid] > 0) ? atomicAdd(&scur_g[tid], hs[tid]) : 0;
  }
  __syncthreads();
#pragma unroll
  for (int k = 0; k < CH_A / 256; ++k) {
    int e = base + k * 256 + tid;
    if (e < EE) {
      int s = ei[e];
      int d = dst[e];
      int dpos = atomicAdd(&cd[d >> 10], 1);
      binned[dpos] = make_int2(s, d);
      int spos = atomicAdd(&cs[s >> 10], 1);
      src_binned[spos] = s;
    }
  }
}

// ---------------------------------------------------------------- Phase B-dst: per-bucket CSR finalize (+ din_is fused)
__global__ __launch_bounds__(1024) void k_csr(const int2* __restrict__ binned,
                                              const int* __restrict__ dbase,
                                              int* __restrict__ offs,
                                              float* __restrict__ din_is,
                                              int* __restrict__ csr_src) {
  __shared__ int h[1024];
  __shared__ int sa[1024];
  __shared__ int cur[1024];
  int tid = threadIdx.x;
  int b = blockIdx.x;
  int dst0 = b << 10;
  int beg = dbase[b];
  int cnt = dbase[b + 1] - beg;

  h[tid] = 0;
  __syncthreads();
  for (int t = tid; t < cnt; t += 1024) {
    atomicAdd(&h[binned[beg + t].y - dst0], 1);
  }
  __syncthreads();
  sa[tid] = h[tid];
  __syncthreads();
  for (int off = 1; off < 1024; off <<= 1) {
    int v = (tid >= off) ? sa[tid - off] : 0;
    __syncthreads();
    sa[tid] += v;
    __syncthreads();
  }
  int excl = sa[tid] - h[tid];
  cur[tid] = beg + excl;
  int node = dst0 + tid;
  if (node < NN) {
    offs[node] = beg + excl;
    int d = h[tid]; if (d < 1) d = 1;
    din_is[node] = rsqrtf((float)d);
  }
  __syncthreads();
  for (int t = tid; t < cnt; t += 1024) {
    int2 p = binned[beg + t];
    int pos = atomicAdd(&cur[p.y - dst0], 1);
    csr_src[pos] = p.x;
  }
}

// ---------------------------------------------------------------- Phase B-src: per-bucket hist -> dout_is
__global__ __launch_bounds__(1024) void k_srchist(const int* __restrict__ src_binned,
                                                  const int* __restrict__ sbase,
                                                  float* __restrict__ dout_is) {
  __shared__ int h[1024];
  int tid = threadIdx.x;
  int b = blockIdx.x;
  int src0 = b << 10;
  int beg = sbase[b];
  int cnt = sbase[b + 1] - beg;
  h[tid] = 0;
  __syncthreads();
  for (int t = tid; t < cnt; t += 1024) {
    atomicAdd(&h[src_binned[beg + t] - src0], 1);
  }
  __syncthreads();
  int node = src0 + tid;
  if (node < NN) {
    int d = h[tid]; if (d < 1) d = 1;
    dout_is[node] = rsqrtf((float)d);
  }
}

// ---------------------------------------------------------------- prescale to fp16
__global__ __launch_bounds__(256) void k_prescale_h(const float* __restrict__ x,
                                                    const float* __restrict__ dout_is,
                                                    __half* __restrict__ xh) {
  int t = blockIdx.x * blockDim.x + threadIdx.x;
  if (t >= NN * (FF / 4)) return;
  int node = t >> 5;
  float sc = dout_is[node];
  float4 v = ((const float4*)x)[t];
  union { __half2 h[2]; uint2 u; } p;
  p.h[0] = __floats2half2_rn(v.x * sc, v.y * sc);
  p.h[1] = __floats2half2_rn(v.z * sc, v.w * sc);
  ((uint2*)xh)[t] = p.u;
}

// ---------------------------------------------------------------- pull aggregation (fp16 gather, fp32 accum)
__global__ __launch_bounds__(256) void k_agg(const __half* __restrict__ xh,
                                             const float* __restrict__ din_is,
                                             const int* __restrict__ offs,
                                             const int* __restrict__ csr_src,
                                             float* __restrict__ out) {
  int gid = blockIdx.x * blockDim.x + threadIdx.x;
  int node = gid >> 6;
  int lane = threadIdx.x & 63;
  if (node >= NN) return;
  int beg = offs[node], end = offs[node + 1];
  float ax = 0.f, ay = 0.f, bx = 0.f, by = 0.f;
  int e = beg;
  for (; e < end && (e & 3); ++e) {
    int s = csr_src[e];
    float2 v = __half22float2(((const __half2*)(xh + (size_t)s * FF))[lane]);
    ax += v.x; ay += v.y;
  }
  for (; e + 8 <= end; e += 8) {
    int4 i0 = *(const int4*)(csr_src + e);
    int4 i1 = *(const int4*)(csr_src + e + 4);
    float2 v0 = __half22float2(((const __half2*)(xh + (size_t)i0.x * FF))[lane]);
    float2 v1 = __half22float2(((const __half2*)(xh + (size_t)i0.y * FF))[lane]);
    float2 v2 = __half22float2(((const __half2*)(xh + (size_t)i0.z * FF))[lane]);
    float2 v3 = __half22float2(((const __half2*)(xh + (size_t)i0.w * FF))[lane]);
    float2 v4 = __half22float2(((const __half2*)(xh + (size_t)i1.x * FF))[lane]);
    float2 v5 = __half22float2(((const __half2*)(xh + (size_t)i1.y * FF))[lane]);
    float2 v6 = __half22float2(((const __half2*)(xh + (size_t)i1.z * FF))[lane]);
    float2 v7 = __half22float2(((const __half2*)(xh + (size_t)i1.w * FF))[lane]);
    ax += v0.x; ay += v0.y; bx += v1.x; by += v1.y;
    ax += v2.x; ay += v2.y; bx += v3.x; by += v3.y;
    ax += v4.x; ay += v4.y; bx += v5.x; by += v5.y;
    ax += v6.x; ay += v6.y; bx += v7.x; by += v7.y;
  }
  for (; e < end; ++e) {
    int s = csr_src[e];
    float2 v = __half22float2(((const __half2*)(xh + (size_t)s * FF))[lane]);
    ax += v.x; ay += v.y;
  }
  float di = din_is[node];
  float2 r; r.x = (ax + bx) * di; r.y = (ay + by) * di;
  *(float2*)(out + node * FF + lane * 2) = r;
}

// ---------------------------------------------------------------- GEMM + bias + PReLU
__global__ __launch_bounds__(256) void k_gemm(const float* __restrict__ X,
                                              const float* __restrict__ W,
                                              const float* __restrict__ bias,
                                              const float* __restrict__ pa,
                                              const float* __restrict__ postscale,
                                              int out_half,
                                              float* __restrict__ outf,
                                              __half* __restrict__ outh) {
  __shared__ float Xs[64][FF + 1];
  __shared__ float Wt[32][FF];
  int tid = threadIdx.x;
  int row0 = blockIdx.x * 64;

  for (int t = tid; t < 64 * (FF / 4); t += 256) {
    int r = t >> 5;
    int c4 = (t & 31) * 4;
    int row = row0 + r;
    float4 v = make_float4(0.f, 0.f, 0.f, 0.f);
    if (row < NN) v = *(const float4*)(X + row * FF + c4);
    Xs[r][c4 + 0] = v.x; Xs[r][c4 + 1] = v.y; Xs[r][c4 + 2] = v.z; Xs[r][c4 + 3] = v.w;
  }

  int rp = tid >> 3;
  int ia = rp * 2, ib = ia + 1;
  int j0 = (tid & 7) * 4;

  float4 acc0q0 = make_float4(0,0,0,0), acc0q1 = acc0q0, acc0q2 = acc0q0, acc0q3 = acc0q0;
  float4 acc1q0 = acc0q0, acc1q1 = acc0q0, acc1q2 = acc0q0, acc1q3 = acc0q0;

  for (int kt = 0; kt < 4; ++kt) {
    __syncthreads();
    {
      const float4* W4 = (const float4*)(W + kt * 32 * FF);
      float4* Wt4 = (float4*)(&Wt[0][0]);
      for (int t = tid; t < 32 * FF / 4; t += 256) Wt4[t] = W4[t];
    }
    __syncthreads();
#pragma unroll
    for (int k = 0; k < 32; ++k) {
      float xa = Xs[ia][kt * 32 + k];
      float xb = Xs[ib][kt * 32 + k];
      float4 w0 = *(const float4*)(&Wt[k][j0 + 0]);
      float4 w1 = *(const float4*)(&Wt[k][j0 + 32]);
      float4 w2 = *(const float4*)(&Wt[k][j0 + 64]);
      float4 w3 = *(const float4*)(&Wt[k][j0 + 96]);
      acc0q0.x = fmaf(xa, w0.x, acc0q0.x); acc0q0.y = fmaf(xa, w0.y, acc0q0.y);
      acc0q0.z = fmaf(xa, w0.z, acc0q0.z); acc0q0.w = fmaf(xa, w0.w, acc0q0.w);
      acc0q1.x = fmaf(xa, w1.x, acc0q1.x); acc0q1.y = fmaf(xa, w1.y, acc0q1.y);
      acc0q1.z = fmaf(xa, w1.z, acc0q1.z); acc0q1.w = fmaf(xa, w1.w, acc0q1.w);
      acc0q2.x = fmaf(xa, w2.x, acc0q2.x); acc0q2.y = fmaf(xa, w2.y, acc0q2.y);
      acc0q2.z = fmaf(xa, w2.z, acc0q2.z); acc0q2.w = fmaf(xa, w2.w, acc0q2.w);
      acc0q3.x = fmaf(xa, w3.x, acc0q3.x); acc0q3.y = fmaf(xa, w3.y, acc0q3.y);
      acc0q3.z = fmaf(xa, w3.z, acc0q3.z); acc0q3.w = fmaf(xa, w3.w, acc0q3.w);
      acc1q0.x = fmaf(xb, w0.x, acc1q0.x); acc1q0.y = fmaf(xb, w0.y, acc1q0.y);
      acc1q0.z = fmaf(xb, w0.z, acc1q0.z); acc1q0.w = fmaf(xb, w0.w, acc1q0.w);
      acc1q1.x = fmaf(xb, w1.x, acc1q1.x); acc1q1.y = fmaf(xb, w1.y, acc1q1.y);
      acc1q1.z = fmaf(xb, w1.z, acc1q1.z); acc1q1.w = fmaf(xb, w1.w, acc1q1.w);
      acc1q2.x = fmaf(xb, w2.x, acc1q2.x); acc1q2.y = fmaf(xb, w2.y, acc1q2.y);
      acc1q2.z = fmaf(xb, w2.z, acc1q2.z); acc1q2.w = fmaf(xb, w2.w, acc1q2.w);
      acc1q3.x = fmaf(xb, w3.x, acc1q3.x); acc1q3.y = fmaf(xb, w3.y, acc1q3.y);
      acc1q3.z = fmaf(xb, w3.z, acc1q3.z); acc1q3.w = fmaf(xb, w3.w, acc1q3.w);
    }
  }

#pragma unroll
  for (int q = 0; q < 4; ++q) {
    int col = j0 + 32 * q;
    float4 b4 = *(const float4*)(bias + col);
    float4 a4 = *(const float4*)(pa + col);
    float4 aq0 = (q == 0) ? acc0q0 : (q == 1) ? acc0q1 : (q == 2) ? acc0q2 : acc0q3;
    float4 aq1 = (q == 0) ? acc1q0 : (q == 1) ? acc1q1 : (q == 2) ? acc1q2 : acc1q3;
#pragma unroll
    for (int h = 0; h < 2; ++h) {
      int row = row0 + (h ? ib : ia);
      float4 aq = h ? aq1 : aq0;
      if (row < NN) {
        float4 v;
        v.x = aq.x + b4.x; v.y = aq.y + b4.y; v.z = aq.z + b4.z; v.w = aq.w + b4.w;
        v.x = v.x >= 0.f ? v.x : a4.x * v.x;
        v.y = v.y >= 0.f ? v.y : a4.y * v.y;
        v.z = v.z >= 0.f ? v.z : a4.z * v.z;
        v.w = v.w >= 0.f ? v.w : a4.w * v.w;
        if (out_half) {
          float ps = postscale[row];
          union { __half2 hh[2]; uint2 u; } p;
          p.hh[0] = __floats2half2_rn(v.x * ps, v.y * ps);
          p.hh[1] = __floats2half2_rn(v.z * ps, v.w * ps);
          *(uint2*)(outh + (size_t)row * FF + col) = p.u;
        } else {
          *(float4*)(outf + (size_t)row * FF + col) = v;
        }
      }
    }
  }
}

// ---------------------------------------------------------------- launch
extern "C" void kernel_launch(void* const* d_in, const int* in_sizes, int n_in,
                              void* d_out, int out_size, void* d_ws, size_t ws_size,
                              hipStream_t stream) {
  const float* features = (const float*)d_in[0];
  const int*   ei       = (const int*)d_in[1];
  const float* W1       = (const float*)d_in[2];
  const float* b1       = (const float*)d_in[3];
  const float* W2       = (const float*)d_in[4];
  const float* b2       = (const float*)d_in[5];
  const float* pa       = (const float*)d_in[6];
  float* out = (float*)d_out;

  char* ws = (char*)d_ws;
  size_t off = 0;
  auto alloc = [&](size_t bytes) -> void* {
    void* p = ws + off;
    off += (bytes + 255) & ~(size_t)255;
    return p;
  };
  int*    buk_tot = (int*)alloc((size_t)2 * NBUK * 4);   // dst_tot | src_tot (one memset)
  int*    dst_tot = buk_tot;
  int*    src_tot = buk_tot + NBUK;
  float*  dout_is = (float*)alloc((size_t)NN * 4);
  float*  din_is  = (float*)alloc((size_t)NN * 4);
  int*    offs    = (int*)alloc((size_t)(NN + 1) * 4);
  int*    dbase   = (int*)alloc((size_t)(NBUK + 1) * 4);
  int*    dcur    = (int*)alloc((size_t)NBUK * 4);
  int*    sbase   = (int*)alloc((size_t)(NBUK + 1) * 4);
  int*    scur    = (int*)alloc((size_t)NBUK * 4);
  int*    csr_src = (int*)alloc((size_t)EE * 4);
  float*  tmp     = (float*)alloc((size_t)NN * FF * 4);
  __half* xh      = (__half*)alloc((size_t)NN * FF * 2);
  int2*   binned     = (int2*)tmp;   // aliases tmp: consumed by k_csr before any agg
  int*    src_binned = (int*)xh;     // aliases xh: consumed by k_srchist before prescale

  hipMemsetAsync(buk_tot, 0, (size_t)2 * NBUK * 4, stream);

  // CSR build + degrees (all LDS-binned, no full-range global atomics)
  k_bukhist2<<<NB_A, 256, 0, stream>>>(ei, dst_tot, src_tot);
  k_bukscan<<<1, 64, 0, stream>>>(dst_tot, src_tot, dbase, dcur, sbase, scur, offs);
  k_bin2<<<NB_A, 256, 0, stream>>>(ei, dcur, scur, binned, src_binned);
  k_csr<<<NBUK, 1024, 0, stream>>>(binned, dbase, offs, din_is, csr_src);
  k_srchist<<<NBUK, 1024, 0, stream>>>(src_binned, sbase, dout_is);

  // layer 1: prescale->xh(half) ; agg(xh)->tmp ; gemm -> xh(half, *dout_is)
  k_prescale_h<<<(NN * FF / 4 + 255) / 256, 256, 0, stream>>>(features, dout_is, xh);
  k_agg<<<NN / 4, 256, 0, stream>>>(xh, din_is, offs, csr_src, tmp);
  k_gemm<<<(NN + 63) / 64, 256, 0, stream>>>(tmp, W1, b1, pa, dout_is, 1, nullptr, xh);

  // layer 2: agg(xh)->tmp ; gemm -> out(fp32)
  k_agg<<<NN / 4, 256, 0, stream>>>(xh, din_is, offs, csr_src, tmp);
  k_gemm<<<(NN + 63) / 64, 256, 0, stream>>>(tmp, W2, b2, pa, nullptr, 0, out, nullptr);
}